// Round 1
// baseline (195.280 us; speedup 1.0000x reference)
//
#include <hip/hip_runtime.h>

typedef __attribute__((ext_vector_type(8))) short short8;
typedef __attribute__((ext_vector_type(4))) float f32x4;

#define DMODEL 256
#define DINNER 512
#define NSTATE 16
#define LSEQ   2048
#define NB     4
#define BL     (NB*LSEQ)      /* 8192 tokens */
#define NCHUNK 32
#define LCHUNK 64
#define LDK    88             /* padded LDS row stride (elements) for GEMM tiles */

__device__ __forceinline__ ushort f2bf(float f) {
  union { float f; unsigned u; } v; v.f = f;
  unsigned u = v.u;
  unsigned r = (u + 0x7fffu + ((u >> 16) & 1u)) >> 16;   // round-nearest-even
  return (ushort)r;
}

// ---------------- converts ----------------
__global__ __launch_bounds__(256) void cvt_k(const float* __restrict__ in,
                                             ushort* __restrict__ out, int n) {
  int i = blockIdx.x * 256 + threadIdx.x;
  if (i < n) out[i] = f2bf(in[i]);
}

// pad x_proj_w [48][512] -> [128][512] bf16 (rows >= 48 zero)
__global__ __launch_bounds__(256) void padw_k(const float* __restrict__ w,
                                              ushort* __restrict__ out) {
  int i = blockIdx.x * 256 + threadIdx.x;
  if (i < 128 * 512) out[i] = ((i >> 9) < 48) ? f2bf(w[i]) : (ushort)0;
}

// ---------------- GEMM: C[M,N] = A[M,K](bf16) * W[N,K](bf16)^T, fp32 out ----
__global__ __launch_bounds__(256) void gemm_bt(const ushort* __restrict__ A,
                                               const ushort* __restrict__ W,
                                               float* __restrict__ C,
                                               int M, int N, int K) {
  __shared__ __align__(16) ushort lA[128 * LDK];
  __shared__ __align__(16) ushort lB[128 * LDK];
  const int t    = threadIdx.x;
  const int lane = t & 63;
  const int wave = t >> 6;
  const int wr = (wave >> 1) * 64;
  const int wc = (wave & 1) * 64;
  const int m0 = blockIdx.x * 128;
  const int n0 = blockIdx.y * 128;
  const int srow = t >> 3;           // 0..31
  const int scol = (t & 7) * 8;      // element col within 64-wide K tile

  f32x4 acc[4][4];
#pragma unroll
  for (int i = 0; i < 4; ++i)
#pragma unroll
    for (int j = 0; j < 4; ++j) acc[i][j] = (f32x4){0.f, 0.f, 0.f, 0.f};

  for (int kt = 0; kt < K; kt += 64) {
#pragma unroll
    for (int cc = 0; cc < 4; ++cc) {
      int r = cc * 32 + srow;
      uint4 va = *reinterpret_cast<const uint4*>(A + (size_t)(m0 + r) * K + kt + scol);
      *reinterpret_cast<uint4*>(&lA[r * LDK + scol]) = va;
      uint4 vb = *reinterpret_cast<const uint4*>(W + (size_t)(n0 + r) * K + kt + scol);
      *reinterpret_cast<uint4*>(&lB[r * LDK + scol]) = vb;
    }
    __syncthreads();
#pragma unroll
    for (int kk = 0; kk < 64; kk += 32) {
      const int ko = kk + (lane >> 4) * 8;
      const int rr = lane & 15;
      short8 af[4], bf[4];
#pragma unroll
      for (int i = 0; i < 4; ++i)
        af[i] = *reinterpret_cast<const short8*>(&lA[(wr + i * 16 + rr) * LDK + ko]);
#pragma unroll
      for (int j = 0; j < 4; ++j)
        bf[j] = *reinterpret_cast<const short8*>(&lB[(wc + j * 16 + rr) * LDK + ko]);
#pragma unroll
      for (int i = 0; i < 4; ++i)
#pragma unroll
        for (int j = 0; j < 4; ++j)
          acc[i][j] = __builtin_amdgcn_mfma_f32_16x16x32_bf16(af[i], bf[j], acc[i][j], 0, 0, 0);
    }
    __syncthreads();
  }
  const int crow = (lane >> 4) * 4;
  const int ccol = lane & 15;
#pragma unroll
  for (int i = 0; i < 4; ++i)
#pragma unroll
    for (int j = 0; j < 4; ++j) {
      int row = m0 + wr + i * 16 + crow;
      int col = n0 + wc + j * 16 + ccol;
#pragma unroll
      for (int r = 0; r < 4; ++r)
        C[(size_t)(row + r) * N + col] = acc[i][j][r];
    }
}

// ---------------- causal depthwise conv (D_CONV=4) + SiLU ----------------
__global__ __launch_bounds__(256) void conv_silu_k(const float* __restrict__ xz,
                                                   const float* __restrict__ cw,
                                                   const float* __restrict__ cb,
                                                   float* __restrict__ xt,
                                                   ushort* __restrict__ xtbf) {
  int idx = blockIdx.x * 256 + threadIdx.x;       // (b,l,e), e fastest
  int e = idx & (DINNER - 1);
  int l = (idx >> 9) & (LSEQ - 1);
  int b = idx >> 20;
  float4 w4 = reinterpret_cast<const float4*>(cw)[e];
  float s = cb[e];
  size_t rb = ((size_t)(b * LSEQ + l)) * 1024 + e;   // xm = xz cols 0..511
  if (l >= 3) s += xz[rb - 3 * 1024] * w4.x;
  if (l >= 2) s += xz[rb - 2 * 1024] * w4.y;
  if (l >= 1) s += xz[rb - 1 * 1024] * w4.z;
  s += xz[rb] * w4.w;
  float sil = s / (1.f + __expf(-s));
  xt[idx] = sil;
  xtbf[idx] = f2bf(sil);
}

// ---------------- delta = softplus(dt @ dt_proj_w^T + b) ----------------
__global__ __launch_bounds__(256) void dtproj_k(const float* __restrict__ dbc,
                                                const float* __restrict__ dtw,
                                                const float* __restrict__ dtb,
                                                float* __restrict__ delta) {
  int idx = blockIdx.x * 256 + threadIdx.x;       // (tok, e)
  int e = idx & (DINNER - 1);
  int tok = idx >> 9;
  const float* dt = dbc + (size_t)tok * 128;      // cols 0..15 of padded dbc
  const float4* wv = reinterpret_cast<const float4*>(dtw + e * 16);
  float s = dtb[e];
#pragma unroll
  for (int q = 0; q < 4; ++q) {
    float4 w4 = wv[q];
    float4 d4 = *reinterpret_cast<const float4*>(dt + q * 4);
    s += w4.x * d4.x + w4.y * d4.y + w4.z * d4.z + w4.w * d4.w;
  }
  delta[idx] = fmaxf(s, 0.f) + log1pf(__expf(-fabsf(s)));
}

// ---------------- scan pass A: per-chunk local scan ----------------
__global__ __launch_bounds__(256) void scanA_k(const float* __restrict__ delta,
                                               const float* __restrict__ xt,
                                               const float* __restrict__ dbc,
                                               const float* __restrict__ A_log,
                                               float* __restrict__ hend,
                                               float* __restrict__ Ssum) {
  int blk = blockIdx.x;                 // b*64 + c*2 + half
  int half = blk & 1, c = (blk >> 1) & (NCHUNK - 1), b = blk >> 6;
  int e = half * 256 + threadIdx.x;
  __shared__ float sB[LCHUNK][NSTATE];
  for (int i = threadIdx.x; i < LCHUNK * NSTATE; i += 256) {
    int li = i >> 4, n = i & 15;
    sB[li][n] = dbc[((size_t)(b * LSEQ + c * LCHUNK + li)) * 128 + 16 + n];
  }
  float An[16], h[16];
  const float4* alv = reinterpret_cast<const float4*>(A_log + e * 16);
#pragma unroll
  for (int q = 0; q < 4; ++q) {
    float4 a4 = alv[q];
    An[q * 4 + 0] = -__expf(a4.x); An[q * 4 + 1] = -__expf(a4.y);
    An[q * 4 + 2] = -__expf(a4.z); An[q * 4 + 3] = -__expf(a4.w);
  }
#pragma unroll
  for (int n = 0; n < 16; ++n) h[n] = 0.f;
  float ssum = 0.f;
  __syncthreads();
  size_t ix = ((size_t)(b * LSEQ + c * LCHUNK)) * DINNER + e;
  for (int i = 0; i < LCHUNK; ++i, ix += DINNER) {
    float d = delta[ix], u = xt[ix];
    float du = d * u;
    ssum += d;
#pragma unroll
    for (int n = 0; n < 16; ++n)
      h[n] = __expf(An[n] * d) * h[n] + du * sB[i][n];
  }
  size_t ob = ((size_t)b * NCHUNK + c) * DINNER + e;
  float4* hp = reinterpret_cast<float4*>(hend + ob * 16);
#pragma unroll
  for (int q = 0; q < 4; ++q) {
    float4 h4; h4.x = h[q*4]; h4.y = h[q*4+1]; h4.z = h[q*4+2]; h4.w = h[q*4+3];
    hp[q] = h4;
  }
  Ssum[ob] = ssum;
}

// ---------------- scan pass B: carry across chunks ----------------
__global__ __launch_bounds__(256) void scanB_k(const float* __restrict__ hend,
                                               const float* __restrict__ Ssum,
                                               const float* __restrict__ A_log,
                                               float* __restrict__ hin) {
  int idx = blockIdx.x * 256 + threadIdx.x;   // (b,e,n)
  int n = idx & 15, e = (idx >> 4) & (DINNER - 1), b = idx >> 13;
  float An = -__expf(A_log[e * 16 + n]);
  float hc = 0.f;
  for (int c = 0; c < NCHUNK; ++c) {
    size_t base = ((size_t)b * NCHUNK + c) * DINNER + e;
    hin[base * 16 + n] = hc;
    hc = __expf(An * Ssum[base]) * hc + hend[base * 16 + n];
  }
}

// ---------------- scan pass C: full scan + skip + gate, bf16 out ----------
__global__ __launch_bounds__(256) void scanC_k(const float* __restrict__ delta,
                                               const float* __restrict__ xt,
                                               const float* __restrict__ dbc,
                                               const float* __restrict__ A_log,
                                               const float* __restrict__ hin,
                                               const float* __restrict__ Dp,
                                               const float* __restrict__ xz,
                                               ushort* __restrict__ ybf) {
  int blk = blockIdx.x;
  int half = blk & 1, c = (blk >> 1) & (NCHUNK - 1), b = blk >> 6;
  int e = half * 256 + threadIdx.x;
  __shared__ float sB[LCHUNK][NSTATE];
  __shared__ float sC[LCHUNK][NSTATE];
  for (int i = threadIdx.x; i < LCHUNK * NSTATE; i += 256) {
    int li = i >> 4, n = i & 15;
    size_t rb = ((size_t)(b * LSEQ + c * LCHUNK + li)) * 128;
    sB[li][n] = dbc[rb + 16 + n];
    sC[li][n] = dbc[rb + 32 + n];
  }
  float An[16], h[16];
  const float4* alv = reinterpret_cast<const float4*>(A_log + e * 16);
#pragma unroll
  for (int q = 0; q < 4; ++q) {
    float4 a4 = alv[q];
    An[q * 4 + 0] = -__expf(a4.x); An[q * 4 + 1] = -__expf(a4.y);
    An[q * 4 + 2] = -__expf(a4.z); An[q * 4 + 3] = -__expf(a4.w);
  }
  size_t hb = (((size_t)b * NCHUNK + c) * DINNER + e) * 16;
  const float4* hv = reinterpret_cast<const float4*>(hin + hb);
#pragma unroll
  for (int q = 0; q < 4; ++q) {
    float4 h4 = hv[q];
    h[q*4] = h4.x; h[q*4+1] = h4.y; h[q*4+2] = h4.z; h[q*4+3] = h4.w;
  }
  float De = Dp[e];
  __syncthreads();
  size_t ix = ((size_t)(b * LSEQ + c * LCHUNK)) * DINNER + e;
  size_t zx = ((size_t)(b * LSEQ + c * LCHUNK)) * 1024 + 512 + e;
  for (int i = 0; i < LCHUNK; ++i, ix += DINNER, zx += 1024) {
    float d = delta[ix], u = xt[ix];
    float du = d * u;
    float y = 0.f;
#pragma unroll
    for (int n = 0; n < 16; ++n) {
      h[n] = __expf(An[n] * d) * h[n] + du * sB[i][n];
      y += h[n] * sC[i][n];
    }
    y += u * De;
    float zv = xz[zx];
    y *= zv / (1.f + __expf(-zv));
    ybf[ix] = f2bf(y);
  }
}

// ---------------- residual + LayerNorm (one wave per token) ----------------
__global__ __launch_bounds__(256) void ln_k(const float* __restrict__ x,
                                            const float* __restrict__ mo,
                                            const float* __restrict__ lw,
                                            const float* __restrict__ lb,
                                            float* __restrict__ lno) {
  int tok = blockIdx.x * 4 + (threadIdx.x >> 6);
  int lane = threadIdx.x & 63;
  size_t base = (size_t)tok * DMODEL + lane * 4;
  float4 xv = *reinterpret_cast<const float4*>(x + base);
  float4 mv = *reinterpret_cast<const float4*>(mo + base);
  float4 v;
  v.x = xv.x + mv.x; v.y = xv.y + mv.y; v.z = xv.z + mv.z; v.w = xv.w + mv.w;
  float s  = v.x + v.y + v.z + v.w;
  float ss = v.x * v.x + v.y * v.y + v.z * v.z + v.w * v.w;
#pragma unroll
  for (int o = 1; o < 64; o <<= 1) {
    s  += __shfl_xor(s, o, 64);
    ss += __shfl_xor(ss, o, 64);
  }
  float mu = s * (1.f / 256.f);
  float var = ss * (1.f / 256.f) - mu * mu;
  float rs = rsqrtf(var + 1e-5f);
  float4 w4 = *reinterpret_cast<const float4*>(lw + lane * 4);
  float4 b4 = *reinterpret_cast<const float4*>(lb + lane * 4);
  float4 o4;
  o4.x = (v.x - mu) * rs * w4.x + b4.x;
  o4.y = (v.y - mu) * rs * w4.y + b4.y;
  o4.z = (v.z - mu) * rs * w4.z + b4.z;
  o4.w = (v.w - mu) * rs * w4.w + b4.w;
  *reinterpret_cast<float4*>(lno + base) = o4;
}

// ---------------- transpose [B,L,D] -> [B,D,L] ----------------
__global__ __launch_bounds__(256) void tr_k(const float* __restrict__ lno,
                                            float* __restrict__ out) {
  __shared__ float tile[32][33];
  int b = blockIdx.z;
  int l0 = blockIdx.x * 32, d0 = blockIdx.y * 32;
  int tx = threadIdx.x & 31, ty = threadIdx.x >> 5;   // ty 0..7
#pragma unroll
  for (int r = ty; r < 32; r += 8)
    tile[r][tx] = lno[((size_t)(b * LSEQ) + l0 + r) * DMODEL + d0 + tx];
  __syncthreads();
#pragma unroll
  for (int r = ty; r < 32; r += 8)
    out[((size_t)(b * DMODEL) + d0 + r) * LSEQ + l0 + tx] = tile[tx][r];
}

extern "C" void kernel_launch(void* const* d_in, const int* in_sizes, int n_in,
                              void* d_out, int out_size, void* d_ws, size_t ws_size,
                              hipStream_t stream) {
  const float* x     = (const float*)d_in[0];
  const float* w_in  = (const float*)d_in[1];
  const float* cw    = (const float*)d_in[2];
  const float* cb    = (const float*)d_in[3];
  const float* w_xp  = (const float*)d_in[4];
  const float* dtw   = (const float*)d_in[5];
  const float* dtb   = (const float*)d_in[6];
  const float* A_log = (const float*)d_in[7];
  const float* Dp    = (const float*)d_in[8];
  const float* w_out = (const float*)d_in[9];
  const float* lw    = (const float*)d_in[10];
  const float* lb    = (const float*)d_in[11];
  float* out = (float*)d_out;

  char* ws = (char*)d_ws;
  size_t off = 0;
  auto alloc = [&](size_t bytes) -> char* {
    char* p = ws + off;
    off += (bytes + 255) & ~(size_t)255;
    return p;
  };
  ushort* xbf   = (ushort*)alloc((size_t)BL * DMODEL * 2);        // 4 MB
  ushort* winb  = (ushort*)alloc((size_t)1024 * 256 * 2);         // 0.5 MB
  ushort* wxpb  = (ushort*)alloc((size_t)128 * 512 * 2);          // 128 KB
  ushort* woutb = (ushort*)alloc((size_t)256 * 512 * 2);          // 256 KB
  float*  xz    = (float*) alloc((size_t)BL * 1024 * 4);          // 32 MB
  float*  xt    = (float*) alloc((size_t)BL * DINNER * 4);        // 16 MB
  ushort* xtbf  = (ushort*)alloc((size_t)BL * DINNER * 2);        // 8 MB
  float*  dbc   = (float*) alloc((size_t)BL * 128 * 4);           // 4 MB
  float*  delta = (float*) alloc((size_t)BL * DINNER * 4);        // 16 MB
  float*  Ssum  = (float*) alloc((size_t)NB * NCHUNK * DINNER * 4);          // 256 KB
  float*  hend  = (float*) alloc((size_t)NB * NCHUNK * DINNER * NSTATE * 4); // 4 MB
  float*  hin   = (float*) alloc((size_t)NB * NCHUNK * DINNER * NSTATE * 4); // 4 MB
  ushort* ybf   = (ushort*)alloc((size_t)BL * DINNER * 2);        // 8 MB
  float*  mo    = (float*) alloc((size_t)BL * DMODEL * 4);        // 8 MB
  float*  lno   = (float*) alloc((size_t)BL * DMODEL * 4);        // 8 MB

  // converts
  cvt_k<<<dim3((BL * DMODEL + 255) / 256), dim3(256), 0, stream>>>(x, xbf, BL * DMODEL);
  cvt_k<<<dim3((1024 * 256 + 255) / 256), dim3(256), 0, stream>>>(w_in, winb, 1024 * 256);
  padw_k<<<dim3((128 * 512 + 255) / 256), dim3(256), 0, stream>>>(w_xp, wxpb);
  cvt_k<<<dim3((256 * 512 + 255) / 256), dim3(256), 0, stream>>>(w_out, woutb, 256 * 512);

  // in_proj: xz[8192,1024] = x[8192,256] @ in_proj_w^T
  gemm_bt<<<dim3(BL / 128, 1024 / 128), dim3(256), 0, stream>>>(xbf, winb, xz, BL, 1024, 256);

  // conv + silu -> xt (fp32 + bf16)
  conv_silu_k<<<dim3(BL * DINNER / 256), dim3(256), 0, stream>>>(xz, cw, cb, xt, xtbf);

  // x_proj: dbc[8192,128(pad)] = xt @ x_proj_w^T
  gemm_bt<<<dim3(BL / 128, 1), dim3(256), 0, stream>>>(xtbf, wxpb, dbc, BL, 128, 512);

  // delta
  dtproj_k<<<dim3(BL * DINNER / 256), dim3(256), 0, stream>>>(dbc, dtw, dtb, delta);

  // chunked scan
  scanA_k<<<dim3(NB * NCHUNK * 2), dim3(256), 0, stream>>>(delta, xt, dbc, A_log, hend, Ssum);
  scanB_k<<<dim3(NB * DINNER * NSTATE / 256), dim3(256), 0, stream>>>(hend, Ssum, A_log, hin);
  scanC_k<<<dim3(NB * NCHUNK * 2), dim3(256), 0, stream>>>(delta, xt, dbc, A_log, hin, Dp, xz, ybf);

  // out_proj: mo[8192,256] = y @ out_proj_w^T
  gemm_bt<<<dim3(BL / 128, 256 / 128), dim3(256), 0, stream>>>(ybf, woutb, mo, BL, 256, 512);

  // residual + LN, then transpose to [B, D, L]
  ln_k<<<dim3(BL / 4), dim3(256), 0, stream>>>(x, mo, lw, lb, lno);
  tr_k<<<dim3(LSEQ / 32, DMODEL / 32, NB), dim3(256), 0, stream>>>(lno, out);
}

// Round 2
// 157.439 us; speedup vs baseline: 1.2404x; 1.2404x over previous
//
#include <hip/hip_runtime.h>

typedef __attribute__((ext_vector_type(8))) short short8;
typedef __attribute__((ext_vector_type(4))) float f32x4;

#define DMODEL 256
#define DINNER 512
#define NSTATE 16
#define LSEQ   2048
#define NB     4
#define BL     (NB*LSEQ)      /* 8192 tokens */
#define NCHUNK 128
#define LCHUNK 16
#define LDK    88             /* padded LDS row stride (elements) for GEMM tiles */

__device__ __forceinline__ ushort f2bf(float f) {
  union { float f; unsigned u; } v; v.f = f;
  unsigned u = v.u;
  unsigned r = (u + 0x7fffu + ((u >> 16) & 1u)) >> 16;   // round-nearest-even
  return (ushort)r;
}

// ---------------- converts ----------------
__global__ __launch_bounds__(256) void cvt_k(const float* __restrict__ in,
                                             ushort* __restrict__ out, int n) {
  int i = blockIdx.x * 256 + threadIdx.x;
  if (i < n) out[i] = f2bf(in[i]);
}

// pad x_proj_w [48][512] -> [128][512] bf16 (rows >= 48 zero)
__global__ __launch_bounds__(256) void padw_k(const float* __restrict__ w,
                                              ushort* __restrict__ out) {
  int i = blockIdx.x * 256 + threadIdx.x;
  if (i < 128 * 512) out[i] = ((i >> 9) < 48) ? f2bf(w[i]) : (ushort)0;
}

// ---------------- GEMM: C[M,N] = A[M,K](bf16) * W[N,K](bf16)^T, fp32 out ----
__global__ __launch_bounds__(256) void gemm_bt(const ushort* __restrict__ A,
                                               const ushort* __restrict__ W,
                                               float* __restrict__ C,
                                               int M, int N, int K) {
  __shared__ __align__(16) ushort lA[128 * LDK];
  __shared__ __align__(16) ushort lB[128 * LDK];
  const int t    = threadIdx.x;
  const int lane = t & 63;
  const int wave = t >> 6;
  const int wr = (wave >> 1) * 64;
  const int wc = (wave & 1) * 64;
  const int m0 = blockIdx.x * 128;
  const int n0 = blockIdx.y * 128;
  const int srow = t >> 3;           // 0..31
  const int scol = (t & 7) * 8;      // element col within 64-wide K tile

  f32x4 acc[4][4];
#pragma unroll
  for (int i = 0; i < 4; ++i)
#pragma unroll
    for (int j = 0; j < 4; ++j) acc[i][j] = (f32x4){0.f, 0.f, 0.f, 0.f};

  for (int kt = 0; kt < K; kt += 64) {
#pragma unroll
    for (int cc = 0; cc < 4; ++cc) {
      int r = cc * 32 + srow;
      uint4 va = *reinterpret_cast<const uint4*>(A + (size_t)(m0 + r) * K + kt + scol);
      *reinterpret_cast<uint4*>(&lA[r * LDK + scol]) = va;
      uint4 vb = *reinterpret_cast<const uint4*>(W + (size_t)(n0 + r) * K + kt + scol);
      *reinterpret_cast<uint4*>(&lB[r * LDK + scol]) = vb;
    }
    __syncthreads();
#pragma unroll
    for (int kk = 0; kk < 64; kk += 32) {
      const int ko = kk + (lane >> 4) * 8;
      const int rr = lane & 15;
      short8 af[4], bf[4];
#pragma unroll
      for (int i = 0; i < 4; ++i)
        af[i] = *reinterpret_cast<const short8*>(&lA[(wr + i * 16 + rr) * LDK + ko]);
#pragma unroll
      for (int j = 0; j < 4; ++j)
        bf[j] = *reinterpret_cast<const short8*>(&lB[(wc + j * 16 + rr) * LDK + ko]);
#pragma unroll
      for (int i = 0; i < 4; ++i)
#pragma unroll
        for (int j = 0; j < 4; ++j)
          acc[i][j] = __builtin_amdgcn_mfma_f32_16x16x32_bf16(af[i], bf[j], acc[i][j], 0, 0, 0);
    }
    __syncthreads();
  }
  const int crow = (lane >> 4) * 4;
  const int ccol = lane & 15;
#pragma unroll
  for (int i = 0; i < 4; ++i)
#pragma unroll
    for (int j = 0; j < 4; ++j) {
      int row = m0 + wr + i * 16 + crow;
      int col = n0 + wc + j * 16 + ccol;
#pragma unroll
      for (int r = 0; r < 4; ++r)
        C[(size_t)(row + r) * N + col] = acc[i][j][r];
    }
}

// ---------------- causal depthwise conv (D_CONV=4) + SiLU ----------------
__global__ __launch_bounds__(256) void conv_silu_k(const float* __restrict__ xz,
                                                   const float* __restrict__ cw,
                                                   const float* __restrict__ cb,
                                                   float* __restrict__ xt,
                                                   ushort* __restrict__ xtbf) {
  int idx = blockIdx.x * 256 + threadIdx.x;       // (b,l,e), e fastest
  int e = idx & (DINNER - 1);
  int l = (idx >> 9) & (LSEQ - 1);
  int b = idx >> 20;
  float4 w4 = reinterpret_cast<const float4*>(cw)[e];
  float s = cb[e];
  size_t rb = ((size_t)(b * LSEQ + l)) * 1024 + e;   // xm = xz cols 0..511
  if (l >= 3) s += xz[rb - 3 * 1024] * w4.x;
  if (l >= 2) s += xz[rb - 2 * 1024] * w4.y;
  if (l >= 1) s += xz[rb - 1 * 1024] * w4.z;
  s += xz[rb] * w4.w;
  float sil = s / (1.f + __expf(-s));
  xt[idx] = sil;
  xtbf[idx] = f2bf(sil);
}

// ---------------- delta = softplus(dt @ dt_proj_w^T + b) ----------------
__global__ __launch_bounds__(256) void dtproj_k(const float* __restrict__ dbc,
                                                const float* __restrict__ dtw,
                                                const float* __restrict__ dtb,
                                                float* __restrict__ delta) {
  int idx = blockIdx.x * 256 + threadIdx.x;       // (tok, e)
  int e = idx & (DINNER - 1);
  int tok = idx >> 9;
  const float* dt = dbc + (size_t)tok * 128;      // cols 0..15 of padded dbc
  const float4* wv = reinterpret_cast<const float4*>(dtw + e * 16);
  float s = dtb[e];
#pragma unroll
  for (int q = 0; q < 4; ++q) {
    float4 w4 = wv[q];
    float4 d4 = *reinterpret_cast<const float4*>(dt + q * 4);
    s += w4.x * d4.x + w4.y * d4.y + w4.z * d4.z + w4.w * d4.w;
  }
  delta[idx] = fmaxf(s, 0.f) + log1pf(__expf(-fabsf(s)));
}

// ---------------- scan pass A: per-chunk local scan ----------------
__global__ __launch_bounds__(256) void scanA_k(const float* __restrict__ delta,
                                               const float* __restrict__ xt,
                                               const float* __restrict__ dbc,
                                               const float* __restrict__ A_log,
                                               float* __restrict__ hend,
                                               float* __restrict__ Ssum) {
  int blk = blockIdx.x;                 // b*(NCHUNK*2) + c*2 + half
  int half = blk & 1, c = (blk >> 1) & (NCHUNK - 1), b = blk >> 8;
  int e = half * 256 + threadIdx.x;
  __shared__ float sB[LCHUNK][NSTATE];
  {
    int i = threadIdx.x;                // LCHUNK*NSTATE == 256
    int li = i >> 4, n = i & 15;
    sB[li][n] = dbc[((size_t)(b * LSEQ + c * LCHUNK + li)) * 128 + 16 + n];
  }
  float An[16], h[16];
  const float4* alv = reinterpret_cast<const float4*>(A_log + e * 16);
#pragma unroll
  for (int q = 0; q < 4; ++q) {
    float4 a4 = alv[q];
    An[q * 4 + 0] = -__expf(a4.x); An[q * 4 + 1] = -__expf(a4.y);
    An[q * 4 + 2] = -__expf(a4.z); An[q * 4 + 3] = -__expf(a4.w);
  }
#pragma unroll
  for (int n = 0; n < 16; ++n) h[n] = 0.f;
  float ssum = 0.f;
  __syncthreads();
  size_t ix = ((size_t)(b * LSEQ + c * LCHUNK)) * DINNER + e;
#pragma unroll
  for (int i = 0; i < LCHUNK; ++i, ix += DINNER) {
    float d = delta[ix], u = xt[ix];
    float du = d * u;
    ssum += d;
#pragma unroll
    for (int n = 0; n < 16; ++n)
      h[n] = __expf(An[n] * d) * h[n] + du * sB[i][n];
  }
  size_t ob = ((size_t)b * NCHUNK + c) * DINNER + e;
  float4* hp = reinterpret_cast<float4*>(hend + ob * 16);
#pragma unroll
  for (int q = 0; q < 4; ++q) {
    float4 h4; h4.x = h[q*4]; h4.y = h[q*4+1]; h4.z = h[q*4+2]; h4.w = h[q*4+3];
    hp[q] = h4;
  }
  Ssum[ob] = ssum;
}

// ------- scan pass B: carry across chunks (in-place: hend -> hin) -------
__global__ __launch_bounds__(256) void scanB_k(float* hend,
                                               const float* __restrict__ Ssum,
                                               const float* __restrict__ A_log) {
  int idx = blockIdx.x * 256 + threadIdx.x;   // (b,e,n)
  int n = idx & 15, e = (idx >> 4) & (DINNER - 1), b = idx >> 13;
  float An = -__expf(A_log[e * 16 + n]);
  float hc = 0.f;
#pragma unroll 4
  for (int c = 0; c < NCHUNK; ++c) {
    size_t base = ((size_t)b * NCHUNK + c) * DINNER + e;
    float s  = Ssum[base];
    float he = hend[base * 16 + n];
    hend[base * 16 + n] = hc;               // hin for chunk c
    hc = __expf(An * s) * hc + he;
  }
}

// ---------------- scan pass C: full scan + skip + gate, bf16 out ----------
__global__ __launch_bounds__(256) void scanC_k(const float* __restrict__ delta,
                                               const float* __restrict__ xt,
                                               const float* __restrict__ dbc,
                                               const float* __restrict__ A_log,
                                               const float* __restrict__ hin,
                                               const float* __restrict__ Dp,
                                               const float* __restrict__ xz,
                                               ushort* __restrict__ ybf) {
  int blk = blockIdx.x;
  int half = blk & 1, c = (blk >> 1) & (NCHUNK - 1), b = blk >> 8;
  int e = half * 256 + threadIdx.x;
  __shared__ float sB[LCHUNK][NSTATE];
  __shared__ float sC[LCHUNK][NSTATE];
  {
    int i = threadIdx.x;                // LCHUNK*NSTATE == 256
    int li = i >> 4, n = i & 15;
    size_t rb = ((size_t)(b * LSEQ + c * LCHUNK + li)) * 128;
    sB[li][n] = dbc[rb + 16 + n];
    sC[li][n] = dbc[rb + 32 + n];
  }
  float An[16], h[16];
  const float4* alv = reinterpret_cast<const float4*>(A_log + e * 16);
#pragma unroll
  for (int q = 0; q < 4; ++q) {
    float4 a4 = alv[q];
    An[q * 4 + 0] = -__expf(a4.x); An[q * 4 + 1] = -__expf(a4.y);
    An[q * 4 + 2] = -__expf(a4.z); An[q * 4 + 3] = -__expf(a4.w);
  }
  size_t hb = (((size_t)b * NCHUNK + c) * DINNER + e) * 16;
  const float4* hv = reinterpret_cast<const float4*>(hin + hb);
#pragma unroll
  for (int q = 0; q < 4; ++q) {
    float4 h4 = hv[q];
    h[q*4] = h4.x; h[q*4+1] = h4.y; h[q*4+2] = h4.z; h[q*4+3] = h4.w;
  }
  float De = Dp[e];
  __syncthreads();
  size_t ix = ((size_t)(b * LSEQ + c * LCHUNK)) * DINNER + e;
  size_t zx = ((size_t)(b * LSEQ + c * LCHUNK)) * 1024 + 512 + e;
#pragma unroll
  for (int i = 0; i < LCHUNK; ++i, ix += DINNER, zx += 1024) {
    float d = delta[ix], u = xt[ix];
    float du = d * u;
    float y = 0.f;
#pragma unroll
    for (int n = 0; n < 16; ++n) {
      h[n] = __expf(An[n] * d) * h[n] + du * sB[i][n];
      y += h[n] * sC[i][n];
    }
    y += u * De;
    float zv = xz[zx];
    y *= zv / (1.f + __expf(-zv));
    ybf[ix] = f2bf(y);
  }
}

// -------- residual + LayerNorm + transpose to [B, D, L], fused --------
__global__ __launch_bounds__(512) void ln_tr_k(const float* __restrict__ x,
                                               const float* __restrict__ mo,
                                               const float* __restrict__ lw,
                                               const float* __restrict__ lb,
                                               float* __restrict__ out) {
  __shared__ float tile[32][257];
  int b = blockIdx.y;
  int l0 = blockIdx.x * 32;
  int wave = threadIdx.x >> 6, lane = threadIdx.x & 63;
  float4 w4 = *reinterpret_cast<const float4*>(lw + lane * 4);
  float4 b4 = *reinterpret_cast<const float4*>(lb + lane * 4);
#pragma unroll
  for (int s = 0; s < 4; ++s) {
    int l = wave * 4 + s;
    size_t base = ((size_t)(b * LSEQ) + l0 + l) * DMODEL + lane * 4;
    float4 xv = *reinterpret_cast<const float4*>(x + base);
    float4 mv = *reinterpret_cast<const float4*>(mo + base);
    float4 v;
    v.x = xv.x + mv.x; v.y = xv.y + mv.y; v.z = xv.z + mv.z; v.w = xv.w + mv.w;
    float sm  = v.x + v.y + v.z + v.w;
    float ss  = v.x * v.x + v.y * v.y + v.z * v.z + v.w * v.w;
#pragma unroll
    for (int o = 1; o < 64; o <<= 1) {
      sm += __shfl_xor(sm, o, 64);
      ss += __shfl_xor(ss, o, 64);
    }
    float mu = sm * (1.f / 256.f);
    float var = ss * (1.f / 256.f) - mu * mu;
    float rs = rsqrtf(var + 1e-5f);
    tile[l][lane * 4 + 0] = (v.x - mu) * rs * w4.x + b4.x;
    tile[l][lane * 4 + 1] = (v.y - mu) * rs * w4.y + b4.y;
    tile[l][lane * 4 + 2] = (v.z - mu) * rs * w4.z + b4.z;
    tile[l][lane * 4 + 3] = (v.w - mu) * rs * w4.w + b4.w;
  }
  __syncthreads();
  int l_i = threadIdx.x & 31;
  int dg = threadIdx.x >> 5;             // 0..15
  size_t ob = ((size_t)b * DMODEL) * LSEQ + l0 + l_i;
#pragma unroll
  for (int d = dg; d < DMODEL; d += 16)
    out[ob + (size_t)d * LSEQ] = tile[l_i][d];
}

extern "C" void kernel_launch(void* const* d_in, const int* in_sizes, int n_in,
                              void* d_out, int out_size, void* d_ws, size_t ws_size,
                              hipStream_t stream) {
  const float* x     = (const float*)d_in[0];
  const float* w_in  = (const float*)d_in[1];
  const float* cw    = (const float*)d_in[2];
  const float* cb    = (const float*)d_in[3];
  const float* w_xp  = (const float*)d_in[4];
  const float* dtw   = (const float*)d_in[5];
  const float* dtb   = (const float*)d_in[6];
  const float* A_log = (const float*)d_in[7];
  const float* Dp    = (const float*)d_in[8];
  const float* w_out = (const float*)d_in[9];
  const float* lw    = (const float*)d_in[10];
  const float* lb    = (const float*)d_in[11];
  float* out = (float*)d_out;

  char* ws = (char*)d_ws;
  size_t off = 0;
  auto alloc = [&](size_t bytes) -> char* {
    char* p = ws + off;
    off += (bytes + 255) & ~(size_t)255;
    return p;
  };
  ushort* xbf   = (ushort*)alloc((size_t)BL * DMODEL * 2);        // 4 MB
  ushort* winb  = (ushort*)alloc((size_t)1024 * 256 * 2);         // 0.5 MB
  ushort* wxpb  = (ushort*)alloc((size_t)128 * 512 * 2);          // 128 KB
  ushort* woutb = (ushort*)alloc((size_t)256 * 512 * 2);          // 256 KB
  float*  xz    = (float*) alloc((size_t)BL * 1024 * 4);          // 32 MB
  float*  xt    = (float*) alloc((size_t)BL * DINNER * 4);        // 16 MB
  ushort* xtbf  = (ushort*)alloc((size_t)BL * DINNER * 2);        // 8 MB
  float*  dbc   = (float*) alloc((size_t)BL * 128 * 4);           // 4 MB
  float*  delta = (float*) alloc((size_t)BL * DINNER * 4);        // 16 MB
  float*  Ssum  = (float*) alloc((size_t)NB * NCHUNK * DINNER * 4);          // 1 MB
  float*  hend  = (float*) alloc((size_t)NB * NCHUNK * DINNER * NSTATE * 4); // 16 MB
  ushort* ybf   = (ushort*)alloc((size_t)BL * DINNER * 2);        // 8 MB
  float*  mo    = (float*) alloc((size_t)BL * DMODEL * 4);        // 8 MB

  // converts
  cvt_k<<<dim3((BL * DMODEL + 255) / 256), dim3(256), 0, stream>>>(x, xbf, BL * DMODEL);
  cvt_k<<<dim3((1024 * 256 + 255) / 256), dim3(256), 0, stream>>>(w_in, winb, 1024 * 256);
  padw_k<<<dim3((128 * 512 + 255) / 256), dim3(256), 0, stream>>>(w_xp, wxpb);
  cvt_k<<<dim3((256 * 512 + 255) / 256), dim3(256), 0, stream>>>(w_out, woutb, 256 * 512);

  // in_proj: xz[8192,1024] = x[8192,256] @ in_proj_w^T
  gemm_bt<<<dim3(BL / 128, 1024 / 128), dim3(256), 0, stream>>>(xbf, winb, xz, BL, 1024, 256);

  // conv + silu -> xt (fp32 + bf16)
  conv_silu_k<<<dim3(BL * DINNER / 256), dim3(256), 0, stream>>>(xz, cw, cb, xt, xtbf);

  // x_proj: dbc[8192,128(pad)] = xt @ x_proj_w^T
  gemm_bt<<<dim3(BL / 128, 1), dim3(256), 0, stream>>>(xtbf, wxpb, dbc, BL, 128, 512);

  // delta
  dtproj_k<<<dim3(BL * DINNER / 256), dim3(256), 0, stream>>>(dbc, dtw, dtb, delta);

  // chunked scan (128 chunks of 16)
  scanA_k<<<dim3(NB * NCHUNK * 2), dim3(256), 0, stream>>>(delta, xt, dbc, A_log, hend, Ssum);
  scanB_k<<<dim3(NB * DINNER * NSTATE / 256), dim3(256), 0, stream>>>(hend, Ssum, A_log);
  scanC_k<<<dim3(NB * NCHUNK * 2), dim3(256), 0, stream>>>(delta, xt, dbc, A_log, hend, Dp, xz, ybf);

  // out_proj: mo[8192,256] = y @ out_proj_w^T
  gemm_bt<<<dim3(BL / 128, 256 / 128), dim3(256), 0, stream>>>(ybf, woutb, mo, BL, 256, 512);

  // residual + LN + transpose to [B, d_model, L]
  ln_tr_k<<<dim3(LSEQ / 32, NB), dim3(512), 0, stream>>>(x, mo, lw, lb, out);
}

// Round 3
// 129.373 us; speedup vs baseline: 1.5094x; 1.2169x over previous
//
#include <hip/hip_runtime.h>

typedef __attribute__((ext_vector_type(8))) short short8;
typedef __attribute__((ext_vector_type(4))) float f32x4;

#define DMODEL 256
#define DINNER 512
#define NSTATE 16
#define LSEQ   2048
#define NB     4
#define BL     (NB*LSEQ)      /* 8192 tokens */
#define NCHUNK 128
#define LCHUNK 16
#define LDK    88             /* padded LDS row stride (elements) for GEMM tiles */

#define NX     (BL*DMODEL)    /* 2097152 */
#define NWIN   (1024*256)     /* 262144  */
#define NWXP   (128*512)      /* 65536   */
#define NWOUT  (256*512)      /* 131072  */

__device__ __forceinline__ ushort f2bf(float f) {
  union { float f; unsigned u; } v; v.f = f;
  unsigned u = v.u;
  unsigned r = (u + 0x7fffu + ((u >> 16) & 1u)) >> 16;   // round-nearest-even
  return (ushort)r;
}
__device__ __forceinline__ float bf2f(ushort u) {
  union { unsigned u; float f; } v; v.u = ((unsigned)u) << 16; return v.f;
}

// ---------------- all weight/input converts in one kernel ----------------
__global__ __launch_bounds__(256) void cvt_all_k(const float* __restrict__ x,
                                                 const float* __restrict__ w_in,
                                                 const float* __restrict__ w_xp,
                                                 const float* __restrict__ w_out,
                                                 ushort* __restrict__ xbf,
                                                 ushort* __restrict__ winb,
                                                 ushort* __restrict__ wxpb,
                                                 ushort* __restrict__ woutb) {
  int i = blockIdx.x * 256 + threadIdx.x;
  if (i < NX) { xbf[i] = f2bf(x[i]); return; }
  i -= NX;
  if (i < NWIN) { winb[i] = f2bf(w_in[i]); return; }
  i -= NWIN;
  if (i < NWXP) { wxpb[i] = ((i >> 9) < 48) ? f2bf(w_xp[i]) : (ushort)0; return; }
  i -= NWXP;
  if (i < NWOUT) woutb[i] = f2bf(w_out[i]);
}

// ------ GEMM: C[M,N] = A[M,K](bf16) * W[N,K](bf16)^T, fp32 or bf16 out ------
template<int BF16OUT>
__global__ __launch_bounds__(256) void gemm_bt(const ushort* __restrict__ A,
                                               const ushort* __restrict__ W,
                                               void* __restrict__ Cv,
                                               int M, int N, int K) {
  __shared__ __align__(16) ushort lA[128 * LDK];
  __shared__ __align__(16) ushort lB[128 * LDK];
  const int t    = threadIdx.x;
  const int lane = t & 63;
  const int wave = t >> 6;
  const int wr = (wave >> 1) * 64;
  const int wc = (wave & 1) * 64;
  const int m0 = blockIdx.x * 128;
  const int n0 = blockIdx.y * 128;
  const int srow = t >> 3;           // 0..31
  const int scol = (t & 7) * 8;      // element col within 64-wide K tile

  f32x4 acc[4][4];
#pragma unroll
  for (int i = 0; i < 4; ++i)
#pragma unroll
    for (int j = 0; j < 4; ++j) acc[i][j] = (f32x4){0.f, 0.f, 0.f, 0.f};

  for (int kt = 0; kt < K; kt += 64) {
#pragma unroll
    for (int cc = 0; cc < 4; ++cc) {
      int r = cc * 32 + srow;
      uint4 va = *reinterpret_cast<const uint4*>(A + (size_t)(m0 + r) * K + kt + scol);
      *reinterpret_cast<uint4*>(&lA[r * LDK + scol]) = va;
      uint4 vb = *reinterpret_cast<const uint4*>(W + (size_t)(n0 + r) * K + kt + scol);
      *reinterpret_cast<uint4*>(&lB[r * LDK + scol]) = vb;
    }
    __syncthreads();
#pragma unroll
    for (int kk = 0; kk < 64; kk += 32) {
      const int ko = kk + (lane >> 4) * 8;
      const int rr = lane & 15;
      short8 af[4], bf[4];
#pragma unroll
      for (int i = 0; i < 4; ++i)
        af[i] = *reinterpret_cast<const short8*>(&lA[(wr + i * 16 + rr) * LDK + ko]);
#pragma unroll
      for (int j = 0; j < 4; ++j)
        bf[j] = *reinterpret_cast<const short8*>(&lB[(wc + j * 16 + rr) * LDK + ko]);
#pragma unroll
      for (int i = 0; i < 4; ++i)
#pragma unroll
        for (int j = 0; j < 4; ++j)
          acc[i][j] = __builtin_amdgcn_mfma_f32_16x16x32_bf16(af[i], bf[j], acc[i][j], 0, 0, 0);
    }
    __syncthreads();
  }
  const int crow = (lane >> 4) * 4;
  const int ccol = lane & 15;
#pragma unroll
  for (int i = 0; i < 4; ++i)
#pragma unroll
    for (int j = 0; j < 4; ++j) {
      int row = m0 + wr + i * 16 + crow;
      int col = n0 + wc + j * 16 + ccol;
      if (BF16OUT) {
        ushort* C = (ushort*)Cv;
#pragma unroll
        for (int r = 0; r < 4; ++r)
          C[(size_t)(row + r) * N + col] = f2bf(acc[i][j][r]);
      } else {
        float* C = (float*)Cv;
#pragma unroll
        for (int r = 0; r < 4; ++r)
          C[(size_t)(row + r) * N + col] = acc[i][j][r];
      }
    }
}

// ------- causal depthwise conv (D_CONV=4) + SiLU; bf16 in/out, 4 e/thread ----
__global__ __launch_bounds__(256) void conv_silu_k(const ushort* __restrict__ xz,
                                                   const float* __restrict__ cw,
                                                   const float* __restrict__ cb,
                                                   ushort* __restrict__ xtbf) {
  int idx = blockIdx.x * 256 + threadIdx.x;       // (token, e4)
  int e4 = idx & 127;
  int t  = idx >> 7;
  int l  = t & (LSEQ - 1);
  int e  = e4 * 4;
  const float4* cwv = reinterpret_cast<const float4*>(cw);
  float4 w0 = cwv[e], w1 = cwv[e + 1], w2 = cwv[e + 2], w3 = cwv[e + 3];
  float4 bb = reinterpret_cast<const float4*>(cb)[e4];
  float s0 = bb.x, s1 = bb.y, s2 = bb.z, s3 = bb.w;
  size_t rb = (size_t)t * 1024 + e;
  {
    ushort4 v = *reinterpret_cast<const ushort4*>(xz + rb);
    s0 += bf2f(v.x) * w0.w; s1 += bf2f(v.y) * w1.w;
    s2 += bf2f(v.z) * w2.w; s3 += bf2f(v.w) * w3.w;
  }
  if (l >= 1) {
    ushort4 v = *reinterpret_cast<const ushort4*>(xz + rb - 1024);
    s0 += bf2f(v.x) * w0.z; s1 += bf2f(v.y) * w1.z;
    s2 += bf2f(v.z) * w2.z; s3 += bf2f(v.w) * w3.z;
  }
  if (l >= 2) {
    ushort4 v = *reinterpret_cast<const ushort4*>(xz + rb - 2048);
    s0 += bf2f(v.x) * w0.y; s1 += bf2f(v.y) * w1.y;
    s2 += bf2f(v.z) * w2.y; s3 += bf2f(v.w) * w3.y;
  }
  if (l >= 3) {
    ushort4 v = *reinterpret_cast<const ushort4*>(xz + rb - 3072);
    s0 += bf2f(v.x) * w0.x; s1 += bf2f(v.y) * w1.x;
    s2 += bf2f(v.z) * w2.x; s3 += bf2f(v.w) * w3.x;
  }
  ushort4 o;
  o.x = f2bf(s0 / (1.f + __expf(-s0)));
  o.y = f2bf(s1 / (1.f + __expf(-s1)));
  o.z = f2bf(s2 / (1.f + __expf(-s2)));
  o.w = f2bf(s3 / (1.f + __expf(-s3)));
  *reinterpret_cast<ushort4*>(xtbf + (size_t)idx * 4) = o;
}

// softplus
__device__ __forceinline__ float sp(float s) {
  float ex = __expf(-fabsf(s));
  return fmaxf(s, 0.f) + __logf(1.f + ex);
}

// ---------------- scan pass A: per-chunk local scan (delta on the fly) -----
__global__ __launch_bounds__(256) void scanA_k(const ushort* __restrict__ xtbf,
                                               const float* __restrict__ dbc,
                                               const float* __restrict__ dtw,
                                               const float* __restrict__ dtb,
                                               const float* __restrict__ A_log,
                                               float* __restrict__ hend,
                                               float* __restrict__ Ssum) {
  int blk = blockIdx.x;                 // b*(NCHUNK*2) + c*2 + half
  int half = blk & 1, c = (blk >> 1) & (NCHUNK - 1), b = blk >> 8;
  int e = half * 256 + threadIdx.x;
  __shared__ float sB[LCHUNK][NSTATE];
  __shared__ float sDt[LCHUNK][NSTATE];
  {
    int i = threadIdx.x;                // LCHUNK*NSTATE == 256
    int li = i >> 4, n = i & 15;
    size_t rb = ((size_t)(b * LSEQ + c * LCHUNK + li)) * 128;
    sDt[li][n] = dbc[rb + n];
    sB[li][n]  = dbc[rb + 16 + n];
  }
  const float4* wv = reinterpret_cast<const float4*>(dtw + e * 16);
  float4 wq0 = wv[0], wq1 = wv[1], wq2 = wv[2], wq3 = wv[3];
  float bias = dtb[e];
  float An[16], h[16];
  const float4* alv = reinterpret_cast<const float4*>(A_log + e * 16);
#pragma unroll
  for (int q = 0; q < 4; ++q) {
    float4 a4 = alv[q];
    An[q * 4 + 0] = -__expf(a4.x); An[q * 4 + 1] = -__expf(a4.y);
    An[q * 4 + 2] = -__expf(a4.z); An[q * 4 + 3] = -__expf(a4.w);
  }
#pragma unroll
  for (int n = 0; n < 16; ++n) h[n] = 0.f;
  float ssum = 0.f;
  __syncthreads();
  size_t ix = ((size_t)(b * LSEQ + c * LCHUNK)) * DINNER + e;
#pragma unroll
  for (int i = 0; i < LCHUNK; ++i, ix += DINNER) {
    float u = bf2f(xtbf[ix]);
    float s = bias;
    s += wq0.x * sDt[i][0]  + wq0.y * sDt[i][1]  + wq0.z * sDt[i][2]  + wq0.w * sDt[i][3];
    s += wq1.x * sDt[i][4]  + wq1.y * sDt[i][5]  + wq1.z * sDt[i][6]  + wq1.w * sDt[i][7];
    s += wq2.x * sDt[i][8]  + wq2.y * sDt[i][9]  + wq2.z * sDt[i][10] + wq2.w * sDt[i][11];
    s += wq3.x * sDt[i][12] + wq3.y * sDt[i][13] + wq3.z * sDt[i][14] + wq3.w * sDt[i][15];
    float d = sp(s);
    ssum += d;
    float du = d * u;
#pragma unroll
    for (int n = 0; n < 16; ++n)
      h[n] = __expf(An[n] * d) * h[n] + du * sB[i][n];
  }
  size_t ob = ((size_t)b * NCHUNK + c) * DINNER + e;
  float4* hp = reinterpret_cast<float4*>(hend + ob * 16);
#pragma unroll
  for (int q = 0; q < 4; ++q) {
    float4 h4; h4.x = h[q*4]; h4.y = h[q*4+1]; h4.z = h[q*4+2]; h4.w = h[q*4+3];
    hp[q] = h4;
  }
  Ssum[ob] = ssum;
}

// ------- scan pass B: carry across chunks (in-place: hend -> hin) -------
__global__ __launch_bounds__(256) void scanB_k(float* hend,
                                               const float* __restrict__ Ssum,
                                               const float* __restrict__ A_log) {
  int idx = blockIdx.x * 256 + threadIdx.x;   // (b,e,n)
  int n = idx & 15, e = (idx >> 4) & (DINNER - 1), b = idx >> 13;
  float An = -__expf(A_log[e * 16 + n]);
  float hc = 0.f;
#pragma unroll 4
  for (int c = 0; c < NCHUNK; ++c) {
    size_t base = ((size_t)b * NCHUNK + c) * DINNER + e;
    float s  = Ssum[base];
    float he = hend[base * 16 + n];
    hend[base * 16 + n] = hc;               // hin for chunk c
    hc = __expf(An * s) * hc + he;
  }
}

// ------ scan pass C: full scan + skip + gate, bf16 out (delta on the fly) ---
__global__ __launch_bounds__(256) void scanC_k(const ushort* __restrict__ xtbf,
                                               const float* __restrict__ dbc,
                                               const float* __restrict__ dtw,
                                               const float* __restrict__ dtb,
                                               const float* __restrict__ A_log,
                                               const float* __restrict__ hin,
                                               const float* __restrict__ Dp,
                                               const ushort* __restrict__ xz,
                                               ushort* __restrict__ ybf) {
  int blk = blockIdx.x;
  int half = blk & 1, c = (blk >> 1) & (NCHUNK - 1), b = blk >> 8;
  int e = half * 256 + threadIdx.x;
  __shared__ float sB[LCHUNK][NSTATE];
  __shared__ float sC[LCHUNK][NSTATE];
  __shared__ float sDt[LCHUNK][NSTATE];
  {
    int i = threadIdx.x;                // LCHUNK*NSTATE == 256
    int li = i >> 4, n = i & 15;
    size_t rb = ((size_t)(b * LSEQ + c * LCHUNK + li)) * 128;
    sDt[li][n] = dbc[rb + n];
    sB[li][n]  = dbc[rb + 16 + n];
    sC[li][n]  = dbc[rb + 32 + n];
  }
  const float4* wv = reinterpret_cast<const float4*>(dtw + e * 16);
  float4 wq0 = wv[0], wq1 = wv[1], wq2 = wv[2], wq3 = wv[3];
  float bias = dtb[e];
  float An[16], h[16];
  const float4* alv = reinterpret_cast<const float4*>(A_log + e * 16);
#pragma unroll
  for (int q = 0; q < 4; ++q) {
    float4 a4 = alv[q];
    An[q * 4 + 0] = -__expf(a4.x); An[q * 4 + 1] = -__expf(a4.y);
    An[q * 4 + 2] = -__expf(a4.z); An[q * 4 + 3] = -__expf(a4.w);
  }
  size_t hb = (((size_t)b * NCHUNK + c) * DINNER + e) * 16;
  const float4* hv = reinterpret_cast<const float4*>(hin + hb);
#pragma unroll
  for (int q = 0; q < 4; ++q) {
    float4 h4 = hv[q];
    h[q*4] = h4.x; h[q*4+1] = h4.y; h[q*4+2] = h4.z; h[q*4+3] = h4.w;
  }
  float De = Dp[e];
  __syncthreads();
  size_t ix = ((size_t)(b * LSEQ + c * LCHUNK)) * DINNER + e;
  size_t zx = ((size_t)(b * LSEQ + c * LCHUNK)) * 1024 + 512 + e;
#pragma unroll
  for (int i = 0; i < LCHUNK; ++i, ix += DINNER, zx += 1024) {
    float u = bf2f(xtbf[ix]);
    float s = bias;
    s += wq0.x * sDt[i][0]  + wq0.y * sDt[i][1]  + wq0.z * sDt[i][2]  + wq0.w * sDt[i][3];
    s += wq1.x * sDt[i][4]  + wq1.y * sDt[i][5]  + wq1.z * sDt[i][6]  + wq1.w * sDt[i][7];
    s += wq2.x * sDt[i][8]  + wq2.y * sDt[i][9]  + wq2.z * sDt[i][10] + wq2.w * sDt[i][11];
    s += wq3.x * sDt[i][12] + wq3.y * sDt[i][13] + wq3.z * sDt[i][14] + wq3.w * sDt[i][15];
    float d = sp(s);
    float du = d * u;
    float y = 0.f;
#pragma unroll
    for (int n = 0; n < 16; ++n) {
      h[n] = __expf(An[n] * d) * h[n] + du * sB[i][n];
      y += h[n] * sC[i][n];
    }
    y += u * De;
    float zv = bf2f(xz[zx]);
    y *= zv / (1.f + __expf(-zv));
    ybf[ix] = f2bf(y);
  }
}

// -------- residual + LayerNorm + transpose to [B, D, L], fused --------
__global__ __launch_bounds__(512) void ln_tr_k(const float* __restrict__ x,
                                               const ushort* __restrict__ mo,
                                               const float* __restrict__ lw,
                                               const float* __restrict__ lb,
                                               float* __restrict__ out) {
  __shared__ float tile[32][257];
  int b = blockIdx.y;
  int l0 = blockIdx.x * 32;
  int wave = threadIdx.x >> 6, lane = threadIdx.x & 63;
  float4 w4 = *reinterpret_cast<const float4*>(lw + lane * 4);
  float4 b4 = *reinterpret_cast<const float4*>(lb + lane * 4);
#pragma unroll
  for (int s = 0; s < 4; ++s) {
    int l = wave * 4 + s;
    size_t base = ((size_t)(b * LSEQ) + l0 + l) * DMODEL + lane * 4;
    float4 xv = *reinterpret_cast<const float4*>(x + base);
    ushort4 mv = *reinterpret_cast<const ushort4*>(mo + base);
    float4 v;
    v.x = xv.x + bf2f(mv.x); v.y = xv.y + bf2f(mv.y);
    v.z = xv.z + bf2f(mv.z); v.w = xv.w + bf2f(mv.w);
    float sm  = v.x + v.y + v.z + v.w;
    float ss  = v.x * v.x + v.y * v.y + v.z * v.z + v.w * v.w;
#pragma unroll
    for (int o = 1; o < 64; o <<= 1) {
      sm += __shfl_xor(sm, o, 64);
      ss += __shfl_xor(ss, o, 64);
    }
    float mu = sm * (1.f / 256.f);
    float var = ss * (1.f / 256.f) - mu * mu;
    float rs = rsqrtf(var + 1e-5f);
    tile[l][lane * 4 + 0] = (v.x - mu) * rs * w4.x + b4.x;
    tile[l][lane * 4 + 1] = (v.y - mu) * rs * w4.y + b4.y;
    tile[l][lane * 4 + 2] = (v.z - mu) * rs * w4.z + b4.z;
    tile[l][lane * 4 + 3] = (v.w - mu) * rs * w4.w + b4.w;
  }
  __syncthreads();
  int l_i = threadIdx.x & 31;
  int dg = threadIdx.x >> 5;             // 0..15
  size_t ob = ((size_t)b * DMODEL) * LSEQ + l0 + l_i;
#pragma unroll
  for (int d = dg; d < DMODEL; d += 16)
    out[ob + (size_t)d * LSEQ] = tile[l_i][d];
}

extern "C" void kernel_launch(void* const* d_in, const int* in_sizes, int n_in,
                              void* d_out, int out_size, void* d_ws, size_t ws_size,
                              hipStream_t stream) {
  const float* x     = (const float*)d_in[0];
  const float* w_in  = (const float*)d_in[1];
  const float* cw    = (const float*)d_in[2];
  const float* cb    = (const float*)d_in[3];
  const float* w_xp  = (const float*)d_in[4];
  const float* dtw   = (const float*)d_in[5];
  const float* dtb   = (const float*)d_in[6];
  const float* A_log = (const float*)d_in[7];
  const float* Dp    = (const float*)d_in[8];
  const float* w_out = (const float*)d_in[9];
  const float* lw    = (const float*)d_in[10];
  const float* lb    = (const float*)d_in[11];
  float* out = (float*)d_out;

  char* ws = (char*)d_ws;
  size_t off = 0;
  auto alloc = [&](size_t bytes) -> char* {
    char* p = ws + off;
    off += (bytes + 255) & ~(size_t)255;
    return p;
  };
  ushort* xbf   = (ushort*)alloc((size_t)BL * DMODEL * 2);        // 4 MB
  ushort* winb  = (ushort*)alloc((size_t)1024 * 256 * 2);         // 0.5 MB
  ushort* wxpb  = (ushort*)alloc((size_t)128 * 512 * 2);          // 128 KB
  ushort* woutb = (ushort*)alloc((size_t)256 * 512 * 2);          // 256 KB
  ushort* xz    = (ushort*)alloc((size_t)BL * 1024 * 2);          // 16 MB
  ushort* xtbf  = (ushort*)alloc((size_t)BL * DINNER * 2);        // 8 MB
  float*  dbc   = (float*) alloc((size_t)BL * 128 * 4);           // 4 MB
  float*  Ssum  = (float*) alloc((size_t)NB * NCHUNK * DINNER * 4);          // 1 MB
  float*  hend  = (float*) alloc((size_t)NB * NCHUNK * DINNER * NSTATE * 4); // 16 MB
  ushort* ybf   = (ushort*)alloc((size_t)BL * DINNER * 2);        // 8 MB
  ushort* mobf  = (ushort*)alloc((size_t)BL * DMODEL * 2);        // 4 MB

  // converts (one kernel)
  cvt_all_k<<<dim3((NX + NWIN + NWXP + NWOUT) / 256), dim3(256), 0, stream>>>(
      x, w_in, w_xp, w_out, xbf, winb, wxpb, woutb);

  // in_proj: xz[8192,1024](bf16) = x[8192,256] @ in_proj_w^T
  gemm_bt<1><<<dim3(BL / 128, 1024 / 128), dim3(256), 0, stream>>>(xbf, winb, xz, BL, 1024, 256);

  // conv + silu -> xtbf
  conv_silu_k<<<dim3(BL * 128 / 256), dim3(256), 0, stream>>>(xz, cw, cb, xtbf);

  // x_proj: dbc[8192,128(pad)](fp32) = xt @ x_proj_w^T
  gemm_bt<0><<<dim3(BL / 128, 1), dim3(256), 0, stream>>>(xtbf, wxpb, dbc, BL, 128, 512);

  // chunked scan (128 chunks of 16); delta recomputed in-kernel
  scanA_k<<<dim3(NB * NCHUNK * 2), dim3(256), 0, stream>>>(xtbf, dbc, dtw, dtb, A_log, hend, Ssum);
  scanB_k<<<dim3(NB * DINNER * NSTATE / 256), dim3(256), 0, stream>>>(hend, Ssum, A_log);
  scanC_k<<<dim3(NB * NCHUNK * 2), dim3(256), 0, stream>>>(xtbf, dbc, dtw, dtb, A_log, hend, Dp, xz, ybf);

  // out_proj: mo[8192,256](bf16) = y @ out_proj_w^T
  gemm_bt<1><<<dim3(BL / 128, 256 / 128), dim3(256), 0, stream>>>(ybf, woutb, mobf, BL, 256, 512);

  // residual + LN + transpose to [B, d_model, L]
  ln_tr_k<<<dim3(LSEQ / 32, NB), dim3(512), 0, stream>>>(x, mobf, lw, lb, out);
}